// Round 1
// baseline (398.917 us; speedup 1.0000x reference)
//
#include <hip/hip_runtime.h>

#define L_DIM 4096
#define C_DIM 256
#define B_DIM 4
#define NH 8
#define DK 32

typedef __bf16 bf16x8 __attribute__((ext_vector_type(8)));
typedef float  f32x4  __attribute__((ext_vector_type(4)));

// ---------------------------------------------------------------------------
// Kernel 1: Q/K/V projections.  q[b,l,o] = sum_c W[o,c] * x[b,c,l]
// Q,K stored [B,H,L,DK] bf16 ; V stored [B,H,DK,L] bf16 (transposed for PV B-frag)
// ---------------------------------------------------------------------------
__global__ __launch_bounds__(256) void proj_qkv_kernel(
    const float* __restrict__ x, const float* __restrict__ Wq,
    const float* __restrict__ Wk, const float* __restrict__ Wv,
    __bf16* __restrict__ Qb, __bf16* __restrict__ Kb, __bf16* __restrict__ Vb)
{
    const int t  = threadIdx.x;
    const int l0 = blockIdx.x * 256;
    const int h  = blockIdx.y % NH;
    const int p  = blockIdx.y / NH;   // 0=Q 1=K 2=V
    const int b  = blockIdx.z;
    const float* W = (p == 0) ? Wq : ((p == 1) ? Wk : Wv);

    __shared__ __attribute__((aligned(16))) float Wt[256][36]; // [c][o] pad->36 for 16B align

    #pragma unroll
    for (int r = 0; r < 32; ++r)
        Wt[t][r] = W[(h * 32 + r) * 256 + t];
    __syncthreads();

    float acc[32];
    #pragma unroll
    for (int o = 0; o < 32; ++o) acc[o] = 0.f;

    const float* xp = x + (size_t)b * C_DIM * L_DIM + l0 + t;
    #pragma unroll 4
    for (int c = 0; c < 256; ++c) {
        float xv = xp[(size_t)c * L_DIM];
        const f32x4* wr = (const f32x4*)&Wt[c][0];
        #pragma unroll
        for (int k = 0; k < 8; ++k) {
            f32x4 w = wr[k];
            acc[k*4+0] += xv * w[0];
            acc[k*4+1] += xv * w[1];
            acc[k*4+2] += xv * w[2];
            acc[k*4+3] += xv * w[3];
        }
    }

    if (p < 2) {
        // [B,H,L,DK]: per-thread 64B contiguous
        __bf16* out = ((p == 0) ? Qb : Kb) + ((size_t)(b*NH + h) * L_DIM + l0 + t) * DK;
        #pragma unroll
        for (int k = 0; k < 4; ++k) {
            bf16x8 pk;
            #pragma unroll
            for (int j = 0; j < 8; ++j) pk[j] = (__bf16)acc[k*8 + j];
            *(bf16x8*)(out + k*8) = pk;
        }
    } else {
        // V: transpose [l][dk] -> [dk][l] via LDS (reuse Wt space)
        __syncthreads();
        __bf16* T = (__bf16*)&Wt[0][0];   // view as [32][258] bf16 = 16512B
        #pragma unroll
        for (int o = 0; o < 32; ++o) T[o*258 + t] = (__bf16)acc[o];
        __syncthreads();
        __bf16* out = Vb + (size_t)(b*NH + h) * DK * L_DIM + l0;
        #pragma unroll
        for (int o = 0; o < 32; ++o)
            out[(size_t)o * L_DIM + t] = T[o*258 + t];
    }
}

// ---------------------------------------------------------------------------
// Kernel 2: flash attention (no running max -- scores are O(1), exp safe in fp32)
// att[b, h*32+d, l] = relu( (sum_k exp(s)·v) / sum_k exp(s) )   stored [B,C,L] bf16
// ---------------------------------------------------------------------------
__global__ __launch_bounds__(256) void attn_kernel(
    const __bf16* __restrict__ Q, const __bf16* __restrict__ K,
    const __bf16* __restrict__ V, __bf16* __restrict__ Att)
{
    const int tid  = threadIdx.x;
    const int wave = tid >> 6;
    const int lane = tid & 63;
    const int m    = lane & 15;
    const int quad = lane >> 4;
    const int bh   = blockIdx.z * NH + blockIdx.y;
    const int q0   = blockIdx.x * 64;

    __shared__ __attribute__((aligned(16))) __bf16 Ks[64][40];    // [kpos][dk]
    __shared__ __attribute__((aligned(16))) __bf16 Vs[32][72];    // [dk][kpos]
    __shared__ __attribute__((aligned(16))) __bf16 Ps[4][16][72]; // per wave [qrow][kpos]

    // Q A-frag: rows q0+wave*16+m, k = quad*8..+8 (held for the whole block)
    const bf16x8 qfrag =
        *(const bf16x8*)(Q + ((size_t)bh * L_DIM + q0 + wave*16 + m) * DK + quad*8);

    f32x4 o0 = {0.f, 0.f, 0.f, 0.f};   // O[qlocal][d0..15]  (D-layout)
    f32x4 o1 = {0.f, 0.f, 0.f, 0.f};   // O[qlocal][d16..31]
    float lsum[4] = {0.f, 0.f, 0.f, 0.f};
    const float kScale = 0.17677669529663687f;   // 1/sqrt(32)

    const __bf16* kbase = K + (size_t)bh * L_DIM * DK + (tid/4)*DK + (tid%4)*8;
    const __bf16* vbase = V + ((size_t)bh * DK + tid/8) * L_DIM + (tid%8)*8;
    __bf16* ksdst = &Ks[tid/4][(tid%4)*8];
    __bf16* vsdst = &Vs[tid/8][(tid%8)*8];

    for (int kt = 0; kt < L_DIM/64; ++kt) {
        __syncthreads();   // previous iter's LDS reads done
        *(bf16x8*)ksdst = *(const bf16x8*)(kbase + (size_t)kt * 64 * DK);
        *(bf16x8*)vsdst = *(const bf16x8*)(vbase + kt * 64);
        __syncthreads();

        // S[16 x 64] = Q Ktile^T : 4 n-tiles, single K-step (DK=32)
        f32x4 s[4];
        #pragma unroll
        for (int nt = 0; nt < 4; ++nt) {
            bf16x8 kfrag = *(const bf16x8*)&Ks[nt*16 + m][quad*8];
            f32x4 z = {0.f, 0.f, 0.f, 0.f};
            s[nt] = __builtin_amdgcn_mfma_f32_16x16x32_bf16(qfrag, kfrag, z, 0, 0, 0);
        }

        // p = exp(s/sqrt(DK)); accumulate row sums; P -> LDS (D-layout -> A-layout)
        #pragma unroll
        for (int nt = 0; nt < 4; ++nt) {
            #pragma unroll
            for (int r = 0; r < 4; ++r) {
                float pv = __expf(s[nt][r] * kScale);
                lsum[r] += pv;
                Ps[wave][quad*4 + r][nt*16 + m] = (__bf16)pv;
            }
        }

        // O += P[16x64] * V[64x32] : 2 k-steps x 2 d-tiles
        #pragma unroll
        for (int ks = 0; ks < 2; ++ks) {
            bf16x8 pfrag = *(const bf16x8*)&Ps[wave][m][ks*32 + quad*8];
            bf16x8 vf0   = *(const bf16x8*)&Vs[m][ks*32 + quad*8];
            bf16x8 vf1   = *(const bf16x8*)&Vs[16 + m][ks*32 + quad*8];
            o0 = __builtin_amdgcn_mfma_f32_16x16x32_bf16(pfrag, vf0, o0, 0, 0, 0);
            o1 = __builtin_amdgcn_mfma_f32_16x16x32_bf16(pfrag, vf1, o1, 0, 0, 0);
        }
    }

    // row sums: reduce across the 16 lanes sharing a quad (same rows)
    #pragma unroll
    for (int r = 0; r < 4; ++r) {
        #pragma unroll
        for (int off = 1; off < 16; off <<= 1)
            lsum[r] += __shfl_xor(lsum[r], off);
    }

    // epilogue: normalize, relu, transpose [qlocal][d] -> [d][qlocal] via per-wave LDS
    __bf16* Osw = &Ps[wave][0][0];   // view as [32][24] bf16 (1536B <= 2304B)
    #pragma unroll
    for (int r = 0; r < 4; ++r) {
        float inv = 1.f / lsum[r];
        float a = o0[r] * inv; a = (a > 0.f) ? a : 0.f;
        float c = o1[r] * inv; c = (c > 0.f) ? c : 0.f;
        Osw[m*24        + quad*4 + r] = (__bf16)a;
        Osw[(16 + m)*24 + quad*4 + r] = (__bf16)c;
    }
    // same-wave LDS dependence; compiler inserts lgkmcnt waits
    const int d    = lane >> 1;
    const int half = lane & 1;
    bf16x8 ov = *(const bf16x8*)&Osw[d*24 + half*8];
    *(bf16x8*)(Att + ((size_t)bh * DK + d) * L_DIM + q0 + wave*16 + half*8) = ov;
}

// ---------------------------------------------------------------------------
// Kernel 3: y[b,o,l] = sum_c Wl[o,c] * att[b,c,l]   (att is [B,C,L] bf16)
// ---------------------------------------------------------------------------
__global__ __launch_bounds__(256) void final_proj_kernel(
    const __bf16* __restrict__ att, const float* __restrict__ Wl,
    float* __restrict__ y)
{
    const int t  = threadIdx.x;
    const int l0 = blockIdx.x * 256;
    const int og = blockIdx.y;        // group of 32 output channels
    const int b  = blockIdx.z;

    __shared__ __attribute__((aligned(16))) float Wt[256][36];
    #pragma unroll
    for (int r = 0; r < 32; ++r)
        Wt[t][r] = Wl[(og*32 + r) * 256 + t];
    __syncthreads();

    float acc[32];
    #pragma unroll
    for (int r = 0; r < 32; ++r) acc[r] = 0.f;

    const __bf16* ap = att + (size_t)b * C_DIM * L_DIM + l0 + t;
    #pragma unroll 4
    for (int c = 0; c < 256; ++c) {
        float av = (float)ap[(size_t)c * L_DIM];
        const f32x4* wr = (const f32x4*)&Wt[c][0];
        #pragma unroll
        for (int k = 0; k < 8; ++k) {
            f32x4 w = wr[k];
            acc[k*4+0] += av * w[0];
            acc[k*4+1] += av * w[1];
            acc[k*4+2] += av * w[2];
            acc[k*4+3] += av * w[3];
        }
    }

    __syncthreads();
    float* T = &Wt[0][0];   // view as [32][257] f32 = 32896B <= 36864B
    #pragma unroll
    for (int r = 0; r < 32; ++r) T[r*257 + t] = acc[r];
    __syncthreads();

    float* out = y + ((size_t)b * C_DIM + og*32) * L_DIM + l0;
    #pragma unroll
    for (int r = 0; r < 32; ++r)
        out[(size_t)r * L_DIM + t] = T[r*257 + t];
}

// ---------------------------------------------------------------------------
extern "C" void kernel_launch(void* const* d_in, const int* in_sizes, int n_in,
                              void* d_out, int out_size, void* d_ws, size_t ws_size,
                              hipStream_t stream)
{
    const float* x  = (const float*)d_in[0];
    const float* Wq = (const float*)d_in[1];
    const float* Wk = (const float*)d_in[2];
    const float* Wv = (const float*)d_in[3];
    const float* Wl = (const float*)d_in[4];
    float* y = (float*)d_out;

    const size_t n = (size_t)B_DIM * NH * L_DIM * DK;   // 4,194,304 elems
    __bf16* Qb = (__bf16*)d_ws;
    __bf16* Kb = Qb + n;
    __bf16* Vb = Kb + n;
    __bf16* Ab = Vb + n;   // att [B,C,L]

    proj_qkv_kernel<<<dim3(L_DIM/256, 3*NH, B_DIM), 256, 0, stream>>>(
        x, Wq, Wk, Wv, Qb, Kb, Vb);
    attn_kernel<<<dim3(L_DIM/64, NH, B_DIM), 256, 0, stream>>>(Qb, Kb, Vb, Ab);
    final_proj_kernel<<<dim3(L_DIM/256, C_DIM/32, B_DIM), 256, 0, stream>>>(Ab, Wl, y);
}